// Round 1
// baseline (5677.259 us; speedup 1.0000x reference)
//
#include <hip/hip_runtime.h>
#include <hip/hip_bf16.h>

#define B_ 128
#define F_ 64
#define R_ 32
#define LOG2F_ 0.693147180559945309f

__device__ __forceinline__ float sspf(float x) {
    // shifted softplus: max(x,0)+log1p(exp(-|x|)) - ln2   (matches jnp.logaddexp(x,0)-ln2)
    return fmaxf(x, 0.0f) + log1pf(__expf(-fabsf(x))) - LOG2F_;
}

__device__ __forceinline__ float bf2f_lo(unsigned int w) { return __uint_as_float(w << 16); }
__device__ __forceinline__ float bf2f_hi(unsigned int w) { return __uint_as_float(w & 0xffff0000u); }
__device__ __forceinline__ unsigned int f2bf(float f) {
    unsigned int u = __float_as_uint(f);
    return (u + 0x7fffu + ((u >> 16) & 1u)) >> 16;   // RNE
}

// ---- detect pairlist dtype on-device (int64 vs int32). Writes 1 if int64. ----
__global__ void detect_kernel(const void* __restrict__ pl, int* __restrict__ flag, int P) {
    const long long* p64 = (const long long*)pl;
    int ok = 1;
    int n = (P < 64) ? P : 64;
    for (int k = 0; k < n; ++k) {
        long long v = p64[k];
        if (v < 0 || v >= 100000000LL) { ok = 0; break; }
    }
    *flag = ok;
}

__global__ void zero_kernel(float4* __restrict__ p, long long n4) {
    long long i = (long long)blockIdx.x * blockDim.x + threadIdx.x;
    if (i < n4) p[i] = make_float4(0.f, 0.f, 0.f, 0.f);
}

// ---- h = x @ w_in + b_in, stored bf16 ----
__global__ __launch_bounds__(256) void h_kernel(
    const float* __restrict__ x, const float* __restrict__ w_in,
    const float* __restrict__ b_in, unsigned short* __restrict__ h, int NA)
{
    int n = blockIdx.x * 256 + threadIdx.x;
    if (n >= NA) return;
    float acc[F_];
    #pragma unroll
    for (int f = 0; f < F_; ++f) acc[f] = b_in[f];
    const float4* xrow = (const float4*)(x + (size_t)n * B_);
    #pragma unroll 2
    for (int rb = 0; rb < B_ / 4; ++rb) {
        float4 xv = xrow[rb];
        const float* w0 = w_in + (size_t)(4 * rb) * F_;
        #pragma unroll
        for (int f = 0; f < F_; ++f) acc[f] = fmaf(xv.x, w0[f], acc[f]);
        #pragma unroll
        for (int f = 0; f < F_; ++f) acc[f] = fmaf(xv.y, w0[F_ + f], acc[f]);
        #pragma unroll
        for (int f = 0; f < F_; ++f) acc[f] = fmaf(xv.z, w0[2 * F_ + f], acc[f]);
        #pragma unroll
        for (int f = 0; f < F_; ++f) acc[f] = fmaf(xv.w, w0[3 * F_ + f], acc[f]);
    }
    uint4* hrow = (uint4*)(h + (size_t)n * F_);
    #pragma unroll
    for (int q = 0; q < F_ / 8; ++q) {
        uint4 ob;
        ob.x = f2bf(acc[8 * q + 0]) | (f2bf(acc[8 * q + 1]) << 16);
        ob.y = f2bf(acc[8 * q + 2]) | (f2bf(acc[8 * q + 3]) << 16);
        ob.z = f2bf(acc[8 * q + 4]) | (f2bf(acc[8 * q + 5]) << 16);
        ob.w = f2bf(acc[8 * q + 6]) | (f2bf(acc[8 * q + 7]) << 16);
        hrow[q] = ob;
    }
}

// ---- fused pair pipeline: Wij = (ssp(f_ij@w1+b1)@w2+b2)*rcut; agg[i] += h[j]*Wij ----
__global__ __launch_bounds__(128) void pair_kernel(
    const float* __restrict__ f_ij, const float* __restrict__ rcut,
    const void* __restrict__ pl, const int* __restrict__ flag,
    const float* __restrict__ w1, const float* __restrict__ b1,
    const float* __restrict__ w2, const float* __restrict__ b2,
    const unsigned short* __restrict__ h, float* __restrict__ agg,
    int P)
{
    __shared__ float t_lds[F_][128];   // [k][tid] -> consecutive lanes = consecutive banks, conflict-free
    int tid = threadIdx.x;
    int p = blockIdx.x * 128 + tid;
    if (p >= P) return;

    // ---- stage 1: t = ssp(f_ij @ w1 + b1) ----
    float acc[F_];
    #pragma unroll
    for (int f = 0; f < F_; ++f) acc[f] = b1[f];
    const float4* frow = (const float4*)(f_ij + (size_t)p * R_);
    for (int rb = 0; rb < R_ / 4; ++rb) {
        float4 fv = frow[rb];
        const float* w0 = w1 + (size_t)(4 * rb) * F_;
        #pragma unroll
        for (int f = 0; f < F_; ++f) acc[f] = fmaf(fv.x, w0[f], acc[f]);
        #pragma unroll
        for (int f = 0; f < F_; ++f) acc[f] = fmaf(fv.y, w0[F_ + f], acc[f]);
        #pragma unroll
        for (int f = 0; f < F_; ++f) acc[f] = fmaf(fv.z, w0[2 * F_ + f], acc[f]);
        #pragma unroll
        for (int f = 0; f < F_; ++f) acc[f] = fmaf(fv.w, w0[3 * F_ + f], acc[f]);
    }
    #pragma unroll
    for (int f = 0; f < F_; ++f) t_lds[f][tid] = sspf(acc[f]);

    // ---- stage 2: wij = t @ w2 + b2 (acc regs reused as wij) ----
    #pragma unroll
    for (int f = 0; f < F_; ++f) acc[f] = b2[f];
    for (int kb = 0; kb < F_ / 4; ++kb) {
        float t0 = t_lds[4 * kb + 0][tid];
        float t1 = t_lds[4 * kb + 1][tid];
        float t2 = t_lds[4 * kb + 2][tid];
        float t3 = t_lds[4 * kb + 3][tid];
        const float* w0 = w2 + (size_t)(4 * kb) * F_;
        #pragma unroll
        for (int f = 0; f < F_; ++f) acc[f] = fmaf(t0, w0[f], acc[f]);
        #pragma unroll
        for (int f = 0; f < F_; ++f) acc[f] = fmaf(t1, w0[F_ + f], acc[f]);
        #pragma unroll
        for (int f = 0; f < F_; ++f) acc[f] = fmaf(t2, w0[2 * F_ + f], acc[f]);
        #pragma unroll
        for (int f = 0; f < F_; ++f) acc[f] = fmaf(t3, w0[3 * F_ + f], acc[f]);
    }

    // ---- gather h[idx_j], modulate, scatter-add to agg[idx_i] ----
    int is64 = *flag;
    long long i_, j_;
    if (is64) {
        const long long* p64 = (const long long*)pl;
        i_ = p64[p];
        j_ = p64[(size_t)P + p];
    } else {
        const int* p32 = (const int*)pl;
        i_ = p32[p];
        j_ = p32[(size_t)P + p];
    }
    float rc = rcut[p];
    const uint4* hjv = (const uint4*)(h + (size_t)j_ * F_);
    float* ai = agg + (size_t)i_ * F_;
    #pragma unroll
    for (int q = 0; q < F_ / 8; ++q) {
        uint4 v = hjv[q];
        float hv0 = bf2f_lo(v.x), hv1 = bf2f_hi(v.x);
        float hv2 = bf2f_lo(v.y), hv3 = bf2f_hi(v.y);
        float hv4 = bf2f_lo(v.z), hv5 = bf2f_hi(v.z);
        float hv6 = bf2f_lo(v.w), hv7 = bf2f_hi(v.w);
        atomicAdd(ai + 8 * q + 0, acc[8 * q + 0] * rc * hv0);
        atomicAdd(ai + 8 * q + 1, acc[8 * q + 1] * rc * hv1);
        atomicAdd(ai + 8 * q + 2, acc[8 * q + 2] * rc * hv2);
        atomicAdd(ai + 8 * q + 3, acc[8 * q + 3] * rc * hv3);
        atomicAdd(ai + 8 * q + 4, acc[8 * q + 4] * rc * hv4);
        atomicAdd(ai + 8 * q + 5, acc[8 * q + 5] * rc * hv5);
        atomicAdd(ai + 8 * q + 6, acc[8 * q + 6] * rc * hv6);
        atomicAdd(ai + 8 * q + 7, acc[8 * q + 7] * rc * hv7);
    }
}

// ---- u = ssp(agg @ w_o1 + b_o1), stored bf16; grid.y = col half ----
__global__ __launch_bounds__(256) void out1_kernel(
    const float* __restrict__ agg, const float* __restrict__ w_o1,
    const float* __restrict__ b_o1, unsigned short* __restrict__ u, int NA)
{
    int n = blockIdx.x * 256 + threadIdx.x;
    if (n >= NA) return;
    int c0 = blockIdx.y * 64;
    float acc[64];
    #pragma unroll
    for (int c = 0; c < 64; ++c) acc[c] = b_o1[c0 + c];
    const float4* arow = (const float4*)(agg + (size_t)n * F_);
    #pragma unroll 2
    for (int rb = 0; rb < F_ / 4; ++rb) {
        float4 av = arow[rb];
        const float* w0 = w_o1 + (size_t)(4 * rb) * B_ + c0;
        #pragma unroll
        for (int c = 0; c < 64; ++c) acc[c] = fmaf(av.x, w0[c], acc[c]);
        #pragma unroll
        for (int c = 0; c < 64; ++c) acc[c] = fmaf(av.y, w0[B_ + c], acc[c]);
        #pragma unroll
        for (int c = 0; c < 64; ++c) acc[c] = fmaf(av.z, w0[2 * B_ + c], acc[c]);
        #pragma unroll
        for (int c = 0; c < 64; ++c) acc[c] = fmaf(av.w, w0[3 * B_ + c], acc[c]);
    }
    uint4* urow = (uint4*)(u + (size_t)n * B_ + c0);
    #pragma unroll
    for (int q = 0; q < 8; ++q) {
        uint4 ob;
        ob.x = f2bf(sspf(acc[8 * q + 0])) | (f2bf(sspf(acc[8 * q + 1])) << 16);
        ob.y = f2bf(sspf(acc[8 * q + 2])) | (f2bf(sspf(acc[8 * q + 3])) << 16);
        ob.z = f2bf(sspf(acc[8 * q + 4])) | (f2bf(sspf(acc[8 * q + 5])) << 16);
        ob.w = f2bf(sspf(acc[8 * q + 6])) | (f2bf(sspf(acc[8 * q + 7])) << 16);
        urow[q] = ob;
    }
}

// ---- out = u @ w_o2 + b_o2 (fp32 out); grid.y = col half ----
__global__ __launch_bounds__(256) void out2_kernel(
    const unsigned short* __restrict__ u, const float* __restrict__ w_o2,
    const float* __restrict__ b_o2, float* __restrict__ out, int NA)
{
    int n = blockIdx.x * 256 + threadIdx.x;
    if (n >= NA) return;
    int c0 = blockIdx.y * 64;
    float acc[64];
    #pragma unroll
    for (int c = 0; c < 64; ++c) acc[c] = b_o2[c0 + c];
    const uint4* urow = (const uint4*)(u + (size_t)n * B_);
    #pragma unroll 2
    for (int kb = 0; kb < B_ / 8; ++kb) {
        uint4 v = urow[kb];
        float uv[8];
        uv[0] = bf2f_lo(v.x); uv[1] = bf2f_hi(v.x);
        uv[2] = bf2f_lo(v.y); uv[3] = bf2f_hi(v.y);
        uv[4] = bf2f_lo(v.z); uv[5] = bf2f_hi(v.z);
        uv[6] = bf2f_lo(v.w); uv[7] = bf2f_hi(v.w);
        #pragma unroll
        for (int e = 0; e < 8; ++e) {
            const float* w0 = w_o2 + (size_t)(8 * kb + e) * B_ + c0;
            #pragma unroll
            for (int c = 0; c < 64; ++c) acc[c] = fmaf(uv[e], w0[c], acc[c]);
        }
    }
    float4* orow = (float4*)(out + (size_t)n * B_ + c0);
    #pragma unroll
    for (int q = 0; q < 16; ++q)
        orow[q] = make_float4(acc[4 * q], acc[4 * q + 1], acc[4 * q + 2], acc[4 * q + 3]);
}

extern "C" void kernel_launch(void* const* d_in, const int* in_sizes, int n_in,
                              void* d_out, int out_size, void* d_ws, size_t ws_size,
                              hipStream_t stream) {
    const float* x    = (const float*)d_in[0];
    const float* f_ij = (const float*)d_in[1];
    const float* rcut = (const float*)d_in[2];
    const void*  pl   = d_in[3];
    const float* w_in = (const float*)d_in[4];
    const float* b_in = (const float*)d_in[5];
    const float* w_f1 = (const float*)d_in[6];
    const float* b_f1 = (const float*)d_in[7];
    const float* w_f2 = (const float*)d_in[8];
    const float* b_f2 = (const float*)d_in[9];
    const float* w_o1 = (const float*)d_in[10];
    const float* b_o1 = (const float*)d_in[11];
    const float* w_o2 = (const float*)d_in[12];
    const float* b_o2 = (const float*)d_in[13];
    float* out = (float*)d_out;

    int NA = in_sizes[0] / B_;
    int P  = in_sizes[2];

    char* ws = (char*)d_ws;
    size_t h_off = 0;
    size_t h_bytes = (size_t)NA * F_ * 2;
    size_t agg_off = (h_off + h_bytes + 255) & ~(size_t)255;
    size_t agg_bytes = (size_t)NA * F_ * 4;
    size_t u_off = (agg_off + agg_bytes + 255) & ~(size_t)255;
    size_t u_bytes = (size_t)NA * B_ * 2;
    size_t flag_off = (u_off + u_bytes + 255) & ~(size_t)255;

    unsigned short* h_buf = (unsigned short*)(ws + h_off);
    float* agg            = (float*)(ws + agg_off);
    unsigned short* u_buf = (unsigned short*)(ws + u_off);
    int* flag             = (int*)(ws + flag_off);

    detect_kernel<<<1, 1, 0, stream>>>(pl, flag, P);
    h_kernel<<<(NA + 255) / 256, 256, 0, stream>>>(x, w_in, b_in, h_buf, NA);
    long long n4 = (long long)NA * F_ / 4;
    zero_kernel<<<(int)((n4 + 255) / 256), 256, 0, stream>>>((float4*)agg, n4);
    pair_kernel<<<(P + 127) / 128, 128, 0, stream>>>(f_ij, rcut, pl, flag,
                                                     w_f1, b_f1, w_f2, b_f2,
                                                     h_buf, agg, P);
    dim3 g3((NA + 255) / 256, 2);
    out1_kernel<<<g3, 256, 0, stream>>>(agg, w_o1, b_o1, u_buf, NA);
    out2_kernel<<<g3, 256, 0, stream>>>(u_buf, w_o2, b_o2, out, NA);
}

// Round 2
// 1081.234 us; speedup vs baseline: 5.2507x; 5.2507x over previous
//
#include <hip/hip_runtime.h>
#include <hip/hip_bf16.h>

#define B_ 128
#define F_ 64
#define R_ 32
#define LOG2F_ 0.693147180559945309f

__device__ __forceinline__ float sspf(float x) {
    // shifted softplus: max(x,0)+log1p(exp(-|x|)) - ln2   (matches jnp.logaddexp(x,0)-ln2)
    return fmaxf(x, 0.0f) + log1pf(__expf(-fabsf(x))) - LOG2F_;
}

__device__ __forceinline__ float bf2f_lo(unsigned int w) { return __uint_as_float(w << 16); }
__device__ __forceinline__ float bf2f_hi(unsigned int w) { return __uint_as_float(w & 0xffff0000u); }
__device__ __forceinline__ unsigned int f2bf(float f) {
    unsigned int u = __float_as_uint(f);
    return (u + 0x7fffu + ((u >> 16) & 1u)) >> 16;   // RNE
}

// ---- detect pairlist dtype on-device (int64 vs int32). Writes 1 if int64. ----
__global__ void detect_kernel(const void* __restrict__ pl, int* __restrict__ flag, int P) {
    const long long* p64 = (const long long*)pl;
    int ok = 1;
    int n = (P < 64) ? P : 64;
    for (int k = 0; k < n; ++k) {
        long long v = p64[k];
        if (v < 0 || v >= 100000000LL) { ok = 0; break; }
    }
    *flag = ok;
}

__global__ void zero_kernel(float4* __restrict__ p, long long n4) {
    long long i = (long long)blockIdx.x * blockDim.x + threadIdx.x;
    if (i < n4) p[i] = make_float4(0.f, 0.f, 0.f, 0.f);
}

// ---- h = x @ w_in + b_in, stored bf16 ----
__global__ __launch_bounds__(256) void h_kernel(
    const float* __restrict__ x, const float* __restrict__ w_in,
    const float* __restrict__ b_in, unsigned short* __restrict__ h, int NA)
{
    int n = blockIdx.x * 256 + threadIdx.x;
    if (n >= NA) return;
    float acc[F_];
    #pragma unroll
    for (int f = 0; f < F_; ++f) acc[f] = b_in[f];
    const float4* xrow = (const float4*)(x + (size_t)n * B_);
    #pragma unroll 2
    for (int rb = 0; rb < B_ / 4; ++rb) {
        float4 xv = xrow[rb];
        const float* w0 = w_in + (size_t)(4 * rb) * F_;
        #pragma unroll
        for (int f = 0; f < F_; ++f) acc[f] = fmaf(xv.x, w0[f], acc[f]);
        #pragma unroll
        for (int f = 0; f < F_; ++f) acc[f] = fmaf(xv.y, w0[F_ + f], acc[f]);
        #pragma unroll
        for (int f = 0; f < F_; ++f) acc[f] = fmaf(xv.z, w0[2 * F_ + f], acc[f]);
        #pragma unroll
        for (int f = 0; f < F_; ++f) acc[f] = fmaf(xv.w, w0[3 * F_ + f], acc[f]);
    }
    uint4* hrow = (uint4*)(h + (size_t)n * F_);
    #pragma unroll
    for (int q = 0; q < F_ / 8; ++q) {
        uint4 ob;
        ob.x = f2bf(acc[8 * q + 0]) | (f2bf(acc[8 * q + 1]) << 16);
        ob.y = f2bf(acc[8 * q + 2]) | (f2bf(acc[8 * q + 3]) << 16);
        ob.z = f2bf(acc[8 * q + 4]) | (f2bf(acc[8 * q + 5]) << 16);
        ob.w = f2bf(acc[8 * q + 6]) | (f2bf(acc[8 * q + 7]) << 16);
        hrow[q] = ob;
    }
}

// ---- fused pair pipeline: Wij = (ssp(f_ij@w1+b1)@w2+b2)*rcut; agg[i] += h[j]*Wij ----
// Scatter restructured: per-pair update transposed through LDS so ONE atomic
// instruction covers the pair's whole contiguous 256B agg row (lane=feature).
__global__ __launch_bounds__(128) void pair_kernel(
    const float* __restrict__ f_ij, const float* __restrict__ rcut,
    const void* __restrict__ pl, const int* __restrict__ flag,
    const float* __restrict__ w1, const float* __restrict__ b1,
    const float* __restrict__ w2, const float* __restrict__ b2,
    const unsigned short* __restrict__ h, float* __restrict__ agg,
    int P)
{
    // S[f][pair_in_block]: columns owned per-thread during compute (no sync
    // needed until the scatter phase). Pad 129: write S[f][tid] consecutive
    // (free); read S[lane][q] stride-129 -> bank = lane+q mod 32, 2-way (free).
    __shared__ float S[F_][129];
    __shared__ int ii[128];
    int tid = threadIdx.x;
    int p = blockIdx.x * 128 + tid;
    bool valid = (p < P);
    int pc = valid ? p : (P > 0 ? P - 1 : 0);   // clamped index for safe loads

    // ---- stage 1: t = ssp(f_ij @ w1 + b1), staged in own LDS column ----
    float acc[F_];
    #pragma unroll
    for (int f = 0; f < F_; ++f) acc[f] = b1[f];
    const float4* frow = (const float4*)(f_ij + (size_t)pc * R_);
    for (int rb = 0; rb < R_ / 4; ++rb) {
        float4 fv = frow[rb];
        const float* w0 = w1 + (size_t)(4 * rb) * F_;
        #pragma unroll
        for (int f = 0; f < F_; ++f) acc[f] = fmaf(fv.x, w0[f], acc[f]);
        #pragma unroll
        for (int f = 0; f < F_; ++f) acc[f] = fmaf(fv.y, w0[F_ + f], acc[f]);
        #pragma unroll
        for (int f = 0; f < F_; ++f) acc[f] = fmaf(fv.z, w0[2 * F_ + f], acc[f]);
        #pragma unroll
        for (int f = 0; f < F_; ++f) acc[f] = fmaf(fv.w, w0[3 * F_ + f], acc[f]);
    }
    #pragma unroll
    for (int f = 0; f < F_; ++f) S[f][tid] = sspf(acc[f]);

    // ---- stage 2: wij = t @ w2 + b2 (acc regs reused as wij) ----
    #pragma unroll
    for (int f = 0; f < F_; ++f) acc[f] = b2[f];
    for (int kb = 0; kb < F_ / 4; ++kb) {
        float t0 = S[4 * kb + 0][tid];
        float t1 = S[4 * kb + 1][tid];
        float t2 = S[4 * kb + 2][tid];
        float t3 = S[4 * kb + 3][tid];
        const float* w0 = w2 + (size_t)(4 * kb) * F_;
        #pragma unroll
        for (int f = 0; f < F_; ++f) acc[f] = fmaf(t0, w0[f], acc[f]);
        #pragma unroll
        for (int f = 0; f < F_; ++f) acc[f] = fmaf(t1, w0[F_ + f], acc[f]);
        #pragma unroll
        for (int f = 0; f < F_; ++f) acc[f] = fmaf(t2, w0[2 * F_ + f], acc[f]);
        #pragma unroll
        for (int f = 0; f < F_; ++f) acc[f] = fmaf(t3, w0[3 * F_ + f], acc[f]);
    }

    // ---- gather h[idx_j], modulate, stage x_ij into own LDS column ----
    int is64 = *flag;
    long long i_ = 0, j_ = 0;
    if (is64) {
        const long long* p64 = (const long long*)pl;
        i_ = p64[pc];
        j_ = p64[(size_t)P + pc];
    } else {
        const int* p32 = (const int*)pl;
        i_ = p32[pc];
        j_ = p32[(size_t)P + pc];
    }
    float rc = valid ? rcut[pc] : 0.0f;
    const uint4* hjv = (const uint4*)(h + (size_t)j_ * F_);
    #pragma unroll
    for (int q = 0; q < F_ / 8; ++q) {
        uint4 v = hjv[q];
        S[8 * q + 0][tid] = acc[8 * q + 0] * rc * bf2f_lo(v.x);
        S[8 * q + 1][tid] = acc[8 * q + 1] * rc * bf2f_hi(v.x);
        S[8 * q + 2][tid] = acc[8 * q + 2] * rc * bf2f_lo(v.y);
        S[8 * q + 3][tid] = acc[8 * q + 3] * rc * bf2f_hi(v.y);
        S[8 * q + 4][tid] = acc[8 * q + 4] * rc * bf2f_lo(v.z);
        S[8 * q + 5][tid] = acc[8 * q + 5] * rc * bf2f_hi(v.z);
        S[8 * q + 6][tid] = acc[8 * q + 6] * rc * bf2f_lo(v.w);
        S[8 * q + 7][tid] = acc[8 * q + 7] * rc * bf2f_hi(v.w);
    }
    ii[tid] = valid ? (int)i_ : -1;
    __syncthreads();

    // ---- scatter: one contiguous 64-lane atomic instruction per pair ----
    int wv = tid >> 6;
    int lane = tid & 63;
    float* base_lane = agg + lane;
    #pragma unroll 4
    for (int qq = 0; qq < 64; ++qq) {
        int q = wv * 64 + qq;
        int iq = __builtin_amdgcn_readfirstlane(ii[q]);   // wave-uniform
        if (iq >= 0) {
            float v = S[lane][q];
            atomicAdd(base_lane + (size_t)iq * F_, v);
        }
    }
}

// ---- u = ssp(agg @ w_o1 + b_o1), stored bf16; grid.y = col half ----
__global__ __launch_bounds__(256) void out1_kernel(
    const float* __restrict__ agg, const float* __restrict__ w_o1,
    const float* __restrict__ b_o1, unsigned short* __restrict__ u, int NA)
{
    int n = blockIdx.x * 256 + threadIdx.x;
    if (n >= NA) return;
    int c0 = blockIdx.y * 64;
    float acc[64];
    #pragma unroll
    for (int c = 0; c < 64; ++c) acc[c] = b_o1[c0 + c];
    const float4* arow = (const float4*)(agg + (size_t)n * F_);
    #pragma unroll 2
    for (int rb = 0; rb < F_ / 4; ++rb) {
        float4 av = arow[rb];
        const float* w0 = w_o1 + (size_t)(4 * rb) * B_ + c0;
        #pragma unroll
        for (int c = 0; c < 64; ++c) acc[c] = fmaf(av.x, w0[c], acc[c]);
        #pragma unroll
        for (int c = 0; c < 64; ++c) acc[c] = fmaf(av.y, w0[B_ + c], acc[c]);
        #pragma unroll
        for (int c = 0; c < 64; ++c) acc[c] = fmaf(av.z, w0[2 * B_ + c], acc[c]);
        #pragma unroll
        for (int c = 0; c < 64; ++c) acc[c] = fmaf(av.w, w0[3 * B_ + c], acc[c]);
    }
    uint4* urow = (uint4*)(u + (size_t)n * B_ + c0);
    #pragma unroll
    for (int q = 0; q < 8; ++q) {
        uint4 ob;
        ob.x = f2bf(sspf(acc[8 * q + 0])) | (f2bf(sspf(acc[8 * q + 1])) << 16);
        ob.y = f2bf(sspf(acc[8 * q + 2])) | (f2bf(sspf(acc[8 * q + 3])) << 16);
        ob.z = f2bf(sspf(acc[8 * q + 4])) | (f2bf(sspf(acc[8 * q + 5])) << 16);
        ob.w = f2bf(sspf(acc[8 * q + 6])) | (f2bf(sspf(acc[8 * q + 7])) << 16);
        urow[q] = ob;
    }
}

// ---- out = u @ w_o2 + b_o2 (fp32 out); grid.y = col half ----
__global__ __launch_bounds__(256) void out2_kernel(
    const unsigned short* __restrict__ u, const float* __restrict__ w_o2,
    const float* __restrict__ b_o2, float* __restrict__ out, int NA)
{
    int n = blockIdx.x * 256 + threadIdx.x;
    if (n >= NA) return;
    int c0 = blockIdx.y * 64;
    float acc[64];
    #pragma unroll
    for (int c = 0; c < 64; ++c) acc[c] = b_o2[c0 + c];
    const uint4* urow = (const uint4*)(u + (size_t)n * B_);
    #pragma unroll 2
    for (int kb = 0; kb < B_ / 8; ++kb) {
        uint4 v = urow[kb];
        float uv[8];
        uv[0] = bf2f_lo(v.x); uv[1] = bf2f_hi(v.x);
        uv[2] = bf2f_lo(v.y); uv[3] = bf2f_hi(v.y);
        uv[4] = bf2f_lo(v.z); uv[5] = bf2f_hi(v.z);
        uv[6] = bf2f_lo(v.w); uv[7] = bf2f_hi(v.w);
        #pragma unroll
        for (int e = 0; e < 8; ++e) {
            const float* w0 = w_o2 + (size_t)(8 * kb + e) * B_ + c0;
            #pragma unroll
            for (int c = 0; c < 64; ++c) acc[c] = fmaf(uv[e], w0[c], acc[c]);
        }
    }
    float4* orow = (float4*)(out + (size_t)n * B_ + c0);
    #pragma unroll
    for (int q = 0; q < 16; ++q)
        orow[q] = make_float4(acc[4 * q], acc[4 * q + 1], acc[4 * q + 2], acc[4 * q + 3]);
}

extern "C" void kernel_launch(void* const* d_in, const int* in_sizes, int n_in,
                              void* d_out, int out_size, void* d_ws, size_t ws_size,
                              hipStream_t stream) {
    const float* x    = (const float*)d_in[0];
    const float* f_ij = (const float*)d_in[1];
    const float* rcut = (const float*)d_in[2];
    const void*  pl   = d_in[3];
    const float* w_in = (const float*)d_in[4];
    const float* b_in = (const float*)d_in[5];
    const float* w_f1 = (const float*)d_in[6];
    const float* b_f1 = (const float*)d_in[7];
    const float* w_f2 = (const float*)d_in[8];
    const float* b_f2 = (const float*)d_in[9];
    const float* w_o1 = (const float*)d_in[10];
    const float* b_o1 = (const float*)d_in[11];
    const float* w_o2 = (const float*)d_in[12];
    const float* b_o2 = (const float*)d_in[13];
    float* out = (float*)d_out;

    int NA = in_sizes[0] / B_;
    int P  = in_sizes[2];

    char* ws = (char*)d_ws;
    size_t h_off = 0;
    size_t h_bytes = (size_t)NA * F_ * 2;
    size_t agg_off = (h_off + h_bytes + 255) & ~(size_t)255;
    size_t agg_bytes = (size_t)NA * F_ * 4;
    size_t u_off = (agg_off + agg_bytes + 255) & ~(size_t)255;
    size_t u_bytes = (size_t)NA * B_ * 2;
    size_t flag_off = (u_off + u_bytes + 255) & ~(size_t)255;

    unsigned short* h_buf = (unsigned short*)(ws + h_off);
    float* agg            = (float*)(ws + agg_off);
    unsigned short* u_buf = (unsigned short*)(ws + u_off);
    int* flag             = (int*)(ws + flag_off);

    detect_kernel<<<1, 1, 0, stream>>>(pl, flag, P);
    h_kernel<<<(NA + 255) / 256, 256, 0, stream>>>(x, w_in, b_in, h_buf, NA);
    long long n4 = (long long)NA * F_ / 4;
    zero_kernel<<<(int)((n4 + 255) / 256), 256, 0, stream>>>((float4*)agg, n4);
    pair_kernel<<<(P + 127) / 128, 128, 0, stream>>>(f_ij, rcut, pl, flag,
                                                     w_f1, b_f1, w_f2, b_f2,
                                                     h_buf, agg, P);
    dim3 g3((NA + 255) / 256, 2);
    out1_kernel<<<g3, 256, 0, stream>>>(agg, w_o1, b_o1, u_buf, NA);
    out2_kernel<<<g3, 256, 0, stream>>>(u_buf, w_o2, b_o2, out, NA);
}

// Round 3
// 662.479 us; speedup vs baseline: 8.5697x; 1.6321x over previous
//
#include <hip/hip_runtime.h>
#include <hip/hip_bf16.h>

#define B_ 128
#define F_ 64
#define R_ 32
#define LOG2F_ 0.693147180559945309f

typedef __attribute__((ext_vector_type(8))) __bf16 bf16x8;
typedef __attribute__((ext_vector_type(8))) short short8;
typedef __attribute__((ext_vector_type(4))) float f32x4;

__device__ __forceinline__ float sspf(float x) {
    // shifted softplus: max(x,0)+log1p(exp(-|x|)) - ln2
    return fmaxf(x, 0.0f) + log1pf(__expf(-fabsf(x))) - LOG2F_;
}

__device__ __forceinline__ float bf2f_lo(unsigned int w) { return __uint_as_float(w << 16); }
__device__ __forceinline__ float bf2f_hi(unsigned int w) { return __uint_as_float(w & 0xffff0000u); }
__device__ __forceinline__ float bfbits2f(unsigned int us) { return __uint_as_float(us << 16); }
__device__ __forceinline__ unsigned int f2bf(float f) {
    unsigned int u = __float_as_uint(f);
    return (u + 0x7fffu + ((u >> 16) & 1u)) >> 16;   // RNE
}

// ---- detect pairlist dtype on-device (int64 vs int32). Writes 1 if int64. ----
__global__ void detect_kernel(const void* __restrict__ pl, int* __restrict__ flag, int P) {
    const long long* p64 = (const long long*)pl;
    int ok = 1;
    int n = (P < 64) ? P : 64;
    for (int k = 0; k < n; ++k) {
        long long v = p64[k];
        if (v < 0 || v >= 100000000LL) { ok = 0; break; }
    }
    *flag = ok;
}

__global__ void zero_kernel(float4* __restrict__ p, long long n4) {
    long long i = (long long)blockIdx.x * blockDim.x + threadIdx.x;
    if (i < n4) p[i] = make_float4(0.f, 0.f, 0.f, 0.f);
}

// ---- h = x @ w_in + b_in, stored bf16 ----
__global__ __launch_bounds__(256) void h_kernel(
    const float* __restrict__ x, const float* __restrict__ w_in,
    const float* __restrict__ b_in, unsigned short* __restrict__ h, int NA)
{
    int n = blockIdx.x * 256 + threadIdx.x;
    if (n >= NA) return;
    float acc[F_];
    #pragma unroll
    for (int f = 0; f < F_; ++f) acc[f] = b_in[f];
    const float4* xrow = (const float4*)(x + (size_t)n * B_);
    #pragma unroll 2
    for (int rb = 0; rb < B_ / 4; ++rb) {
        float4 xv = xrow[rb];
        const float* w0 = w_in + (size_t)(4 * rb) * F_;
        #pragma unroll
        for (int f = 0; f < F_; ++f) acc[f] = fmaf(xv.x, w0[f], acc[f]);
        #pragma unroll
        for (int f = 0; f < F_; ++f) acc[f] = fmaf(xv.y, w0[F_ + f], acc[f]);
        #pragma unroll
        for (int f = 0; f < F_; ++f) acc[f] = fmaf(xv.z, w0[2 * F_ + f], acc[f]);
        #pragma unroll
        for (int f = 0; f < F_; ++f) acc[f] = fmaf(xv.w, w0[3 * F_ + f], acc[f]);
    }
    uint4* hrow = (uint4*)(h + (size_t)n * F_);
    #pragma unroll
    for (int q = 0; q < F_ / 8; ++q) {
        uint4 ob;
        ob.x = f2bf(acc[8 * q + 0]) | (f2bf(acc[8 * q + 1]) << 16);
        ob.y = f2bf(acc[8 * q + 2]) | (f2bf(acc[8 * q + 3]) << 16);
        ob.z = f2bf(acc[8 * q + 4]) | (f2bf(acc[8 * q + 5]) << 16);
        ob.w = f2bf(acc[8 * q + 6]) | (f2bf(acc[8 * q + 7]) << 16);
        hrow[q] = ob;
    }
}

// ---- MFMA fused pair pipeline ----
// Block = 256 pairs, 4 waves, 64 pairs/wave. Stage1: C1[64p x 64f] via 16
// mfma_16x16x32 (K=32). ssp -> bf16 -> XOR-swizzled LDS T. Stage2: C2 via 32
// MFMA (K=64). Scatter directly from C2 regs: one 64-lane atomic per (rt,ct,r)
// covers 4 pairs x 16 feats (4x 64B segments). No cross-wave deps -> no barriers.
__global__ __launch_bounds__(256, 3) void pair_kernel(
    const float* __restrict__ f_ij, const float* __restrict__ rcut,
    const void* __restrict__ pl, const int* __restrict__ flag,
    const float* __restrict__ w1, const float* __restrict__ b1,
    const float* __restrict__ w2, const float* __restrict__ b2,
    const unsigned short* __restrict__ h, float* __restrict__ agg,
    int P)
{
    __shared__ __align__(16) unsigned short T[256 * 64];  // swizzled [pair][feat] bf16
    __shared__ __align__(16) int   ii[256];
    __shared__ __align__(16) int   jj[256];
    __shared__ __align__(16) float rr[256];

    const int tid   = threadIdx.x;
    const int lane  = tid & 63;
    const int wv    = tid >> 6;
    const int g     = lane >> 4;     // 16-lane group
    const int m     = lane & 15;
    const int pbase = blockIdx.x * 256;
    const int wbase = wv * 64;       // this wave's 64 pairs (block-local)

    // ---- phase 0: pair metadata -> LDS (own wave's slots only) ----
    {
        int p = pbase + tid;
        bool valid = (p < P);
        int pc = valid ? p : (P > 0 ? P - 1 : 0);
        long long i_, j_;
        if (*flag) {
            const long long* p64 = (const long long*)pl;
            i_ = p64[pc]; j_ = p64[(size_t)P + pc];
        } else {
            const int* p32 = (const int*)pl;
            i_ = p32[pc]; j_ = p32[(size_t)P + pc];
        }
        ii[tid] = valid ? (int)i_ : 0;   // invalid -> row 0 with rc=0 (adds 0.0)
        jj[tid] = valid ? (int)j_ : 0;
        rr[tid] = valid ? rcut[pc] : 0.0f;
    }

    // ---- weight B-fragments (loaded once; L1/L2-resident) ----
    // B-frag layout (16x16x32): lane holds B[k=(l>>4)*8+i][n=l&15]
    short8 b1f[4];
    #pragma unroll
    for (int ct = 0; ct < 4; ++ct)
        #pragma unroll
        for (int i = 0; i < 8; ++i)
            b1f[ct][i] = (short)f2bf(w1[(g * 8 + i) * F_ + ct * 16 + m]);
    short8 b2f[2][4];
    #pragma unroll
    for (int kh = 0; kh < 2; ++kh)
        #pragma unroll
        for (int ct = 0; ct < 4; ++ct)
            #pragma unroll
            for (int i = 0; i < 8; ++i)
                b2f[kh][ct][i] = (short)f2bf(w2[(kh * 32 + g * 8 + i) * F_ + ct * 16 + m]);

    float bias1[4], bias2[4];
    #pragma unroll
    for (int ct = 0; ct < 4; ++ct) {
        bias1[ct] = b1[ct * 16 + m];
        bias2[ct] = b2[ct * 16 + m];
    }

    // ---- stage 1: C1 = f_ij @ W1 ----
    // A-frag: lane holds A[row=l&15][k=(l>>4)*8+i]; direct from global (coalesced)
    f32x4 C1[4][4];
    #pragma unroll
    for (int rt = 0; rt < 4; ++rt) {
        int row = pbase + wbase + rt * 16 + m;
        if (row >= P) row = (P > 0 ? P - 1 : 0);
        const float* src = f_ij + (size_t)row * R_ + g * 8;
        short8 a;
        #pragma unroll
        for (int i = 0; i < 8; ++i) a[i] = (short)f2bf(src[i]);
        bf16x8 av = __builtin_bit_cast(bf16x8, a);
        #pragma unroll
        for (int ct = 0; ct < 4; ++ct) {
            f32x4 z = {0.f, 0.f, 0.f, 0.f};
            C1[rt][ct] = __builtin_amdgcn_mfma_f32_16x16x32_bf16(
                av, __builtin_bit_cast(bf16x8, b1f[ct]), z, 0, 0, 0);
        }
    }

    // ---- ssp + bf16 -> swizzled T.  C/D: pair=(l>>4)*4+r (+rt*16), feat=ct*16+(l&15) ----
    #pragma unroll
    for (int rt = 0; rt < 4; ++rt)
        #pragma unroll
        for (int ct = 0; ct < 4; ++ct)
            #pragma unroll
            for (int r = 0; r < 4; ++r) {
                int p = wbase + rt * 16 + g * 4 + r;
                int fcol = ct * 16 + m;
                float tv = sspf(C1[rt][ct][r] + bias1[ct]);
                int chunk = (fcol >> 3) ^ (p & 7);          // XOR-swizzle 16B chunks
                T[p * 64 + chunk * 8 + (fcol & 7)] = (unsigned short)f2bf(tv);
            }

    // ---- stage 2: C2 = T @ W2 (K=64 -> 2 MFMA) ----
    f32x4 C2[4][4];
    #pragma unroll
    for (int rt = 0; rt < 4; ++rt) {
        int p = wbase + rt * 16 + m;
        int s = p & 7;
        bf16x8 a0 = *(const bf16x8*)&T[p * 64 + ((0 * 4 + g) ^ s) * 8];
        bf16x8 a1 = *(const bf16x8*)&T[p * 64 + ((1 * 4 + g) ^ s) * 8];
        #pragma unroll
        for (int ct = 0; ct < 4; ++ct) {
            f32x4 c = {0.f, 0.f, 0.f, 0.f};
            c = __builtin_amdgcn_mfma_f32_16x16x32_bf16(
                a0, __builtin_bit_cast(bf16x8, b2f[0][ct]), c, 0, 0, 0);
            c = __builtin_amdgcn_mfma_f32_16x16x32_bf16(
                a1, __builtin_bit_cast(bf16x8, b2f[1][ct]), c, 0, 0, 0);
            C2[rt][ct] = c;
        }
    }

    // ---- epilogue: wij*rc*h[j] -> atomic scatter straight from C2 regs ----
    #pragma unroll
    for (int rt = 0; rt < 4; ++rt) {
        int base = wbase + rt * 16 + g * 4;
        int4   iv = *(const int4*)&ii[base];
        int4   jv = *(const int4*)&jj[base];
        float4 rv = *(const float4*)&rr[base];
        int   ia[4] = {iv.x, iv.y, iv.z, iv.w};
        int   ja[4] = {jv.x, jv.y, jv.z, jv.w};
        float ra[4] = {rv.x, rv.y, rv.z, rv.w};
        #pragma unroll
        for (int ct = 0; ct < 4; ++ct) {
            int fcol = ct * 16 + m;
            #pragma unroll
            for (int r = 0; r < 4; ++r) {
                float wij = C2[rt][ct][r] + bias2[ct];
                float hv = bfbits2f(h[(size_t)ja[r] * F_ + fcol]);
                float val = wij * ra[r] * hv;
                atomicAdd(agg + (size_t)ia[r] * F_ + fcol, val);
            }
        }
    }
}

// ---- u = ssp(agg @ w_o1 + b_o1), stored bf16; grid.y = col half ----
__global__ __launch_bounds__(256) void out1_kernel(
    const float* __restrict__ agg, const float* __restrict__ w_o1,
    const float* __restrict__ b_o1, unsigned short* __restrict__ u, int NA)
{
    int n = blockIdx.x * 256 + threadIdx.x;
    if (n >= NA) return;
    int c0 = blockIdx.y * 64;
    float acc[64];
    #pragma unroll
    for (int c = 0; c < 64; ++c) acc[c] = b_o1[c0 + c];
    const float4* arow = (const float4*)(agg + (size_t)n * F_);
    #pragma unroll 2
    for (int rb = 0; rb < F_ / 4; ++rb) {
        float4 av = arow[rb];
        const float* w0 = w_o1 + (size_t)(4 * rb) * B_ + c0;
        #pragma unroll
        for (int c = 0; c < 64; ++c) acc[c] = fmaf(av.x, w0[c], acc[c]);
        #pragma unroll
        for (int c = 0; c < 64; ++c) acc[c] = fmaf(av.y, w0[B_ + c], acc[c]);
        #pragma unroll
        for (int c = 0; c < 64; ++c) acc[c] = fmaf(av.z, w0[2 * B_ + c], acc[c]);
        #pragma unroll
        for (int c = 0; c < 64; ++c) acc[c] = fmaf(av.w, w0[3 * B_ + c], acc[c]);
    }
    uint4* urow = (uint4*)(u + (size_t)n * B_ + c0);
    #pragma unroll
    for (int q = 0; q < 8; ++q) {
        uint4 ob;
        ob.x = f2bf(sspf(acc[8 * q + 0])) | (f2bf(sspf(acc[8 * q + 1])) << 16);
        ob.y = f2bf(sspf(acc[8 * q + 2])) | (f2bf(sspf(acc[8 * q + 3])) << 16);
        ob.z = f2bf(sspf(acc[8 * q + 4])) | (f2bf(sspf(acc[8 * q + 5])) << 16);
        ob.w = f2bf(sspf(acc[8 * q + 6])) | (f2bf(sspf(acc[8 * q + 7])) << 16);
        urow[q] = ob;
    }
}

// ---- out = u @ w_o2 + b_o2 (fp32 out); grid.y = col half ----
__global__ __launch_bounds__(256) void out2_kernel(
    const unsigned short* __restrict__ u, const float* __restrict__ w_o2,
    const float* __restrict__ b_o2, float* __restrict__ out, int NA)
{
    int n = blockIdx.x * 256 + threadIdx.x;
    if (n >= NA) return;
    int c0 = blockIdx.y * 64;
    float acc[64];
    #pragma unroll
    for (int c = 0; c < 64; ++c) acc[c] = b_o2[c0 + c];
    const uint4* urow = (const uint4*)(u + (size_t)n * B_);
    #pragma unroll 2
    for (int kb = 0; kb < B_ / 8; ++kb) {
        uint4 v = urow[kb];
        float uv[8];
        uv[0] = bf2f_lo(v.x); uv[1] = bf2f_hi(v.x);
        uv[2] = bf2f_lo(v.y); uv[3] = bf2f_hi(v.y);
        uv[4] = bf2f_lo(v.z); uv[5] = bf2f_hi(v.z);
        uv[6] = bf2f_lo(v.w); uv[7] = bf2f_hi(v.w);
        #pragma unroll
        for (int e = 0; e < 8; ++e) {
            const float* w0 = w_o2 + (size_t)(8 * kb + e) * B_ + c0;
            #pragma unroll
            for (int c = 0; c < 64; ++c) acc[c] = fmaf(uv[e], w0[c], acc[c]);
        }
    }
    float4* orow = (float4*)(out + (size_t)n * B_ + c0);
    #pragma unroll
    for (int q = 0; q < 16; ++q)
        orow[q] = make_float4(acc[4 * q], acc[4 * q + 1], acc[4 * q + 2], acc[4 * q + 3]);
}

extern "C" void kernel_launch(void* const* d_in, const int* in_sizes, int n_in,
                              void* d_out, int out_size, void* d_ws, size_t ws_size,
                              hipStream_t stream) {
    const float* x    = (const float*)d_in[0];
    const float* f_ij = (const float*)d_in[1];
    const float* rcut = (const float*)d_in[2];
    const void*  pl   = d_in[3];
    const float* w_in = (const float*)d_in[4];
    const float* b_in = (const float*)d_in[5];
    const float* w_f1 = (const float*)d_in[6];
    const float* b_f1 = (const float*)d_in[7];
    const float* w_f2 = (const float*)d_in[8];
    const float* b_f2 = (const float*)d_in[9];
    const float* w_o1 = (const float*)d_in[10];
    const float* b_o1 = (const float*)d_in[11];
    const float* w_o2 = (const float*)d_in[12];
    const float* b_o2 = (const float*)d_in[13];
    float* out = (float*)d_out;

    int NA = in_sizes[0] / B_;
    int P  = in_sizes[2];

    char* ws = (char*)d_ws;
    size_t h_off = 0;
    size_t h_bytes = (size_t)NA * F_ * 2;
    size_t agg_off = (h_off + h_bytes + 255) & ~(size_t)255;
    size_t agg_bytes = (size_t)NA * F_ * 4;
    size_t u_off = (agg_off + agg_bytes + 255) & ~(size_t)255;
    size_t u_bytes = (size_t)NA * B_ * 2;
    size_t flag_off = (u_off + u_bytes + 255) & ~(size_t)255;

    unsigned short* h_buf = (unsigned short*)(ws + h_off);
    float* agg            = (float*)(ws + agg_off);
    unsigned short* u_buf = (unsigned short*)(ws + u_off);
    int* flag             = (int*)(ws + flag_off);

    detect_kernel<<<1, 1, 0, stream>>>(pl, flag, P);
    h_kernel<<<(NA + 255) / 256, 256, 0, stream>>>(x, w_in, b_in, h_buf, NA);
    long long n4 = (long long)NA * F_ / 4;
    zero_kernel<<<(int)((n4 + 255) / 256), 256, 0, stream>>>((float4*)agg, n4);
    pair_kernel<<<(P + 255) / 256, 256, 0, stream>>>(f_ij, rcut, pl, flag,
                                                     w_f1, b_f1, w_f2, b_f2,
                                                     h_buf, agg, P);
    dim3 g3((NA + 255) / 256, 2);
    out1_kernel<<<g3, 256, 0, stream>>>(agg, w_o1, b_o1, u_buf, NA);
    out2_kernel<<<g3, 256, 0, stream>>>(u_buf, w_o2, b_o2, out, NA);
}

// Round 4
// 537.280 us; speedup vs baseline: 10.5667x; 1.2330x over previous
//
#include <hip/hip_runtime.h>
#include <hip/hip_bf16.h>

#define B_ 128
#define F_ 64
#define R_ 32

typedef __attribute__((ext_vector_type(8))) __bf16 bf16x8;
typedef __attribute__((ext_vector_type(8))) short short8;
typedef __attribute__((ext_vector_type(4))) float f32x4;

__device__ __forceinline__ float sspf(float x) {
    // shifted softplus = max(x,0) + log(1+exp(-|x|)) - ln2 ... the -ln2 is folded
    // by caller? NO: keep it here. Uses v_exp/v_log fast paths (~7 VALU).
    return fmaxf(x, 0.0f) + __logf(1.0f + __expf(-fabsf(x))) - 0.6931471805599453f;
}

__device__ __forceinline__ float bf2f_lo(unsigned int w) { return __uint_as_float(w << 16); }
__device__ __forceinline__ float bf2f_hi(unsigned int w) { return __uint_as_float(w & 0xffff0000u); }
__device__ __forceinline__ float bfbits2f(unsigned int us) { return __uint_as_float(us << 16); }
__device__ __forceinline__ unsigned int f2bf(float f) {
    unsigned int u = __float_as_uint(f);
    return (u + 0x7fffu + ((u >> 16) & 1u)) >> 16;   // RNE
}

// ---- detect pairlist dtype on-device (int64 vs int32). Writes 1 if int64. ----
__global__ void detect_kernel(const void* __restrict__ pl, int* __restrict__ flag, int P) {
    const long long* p64 = (const long long*)pl;
    int ok = 1;
    int n = (P < 64) ? P : 64;
    for (int k = 0; k < n; ++k) {
        long long v = p64[k];
        if (v < 0 || v >= 100000000LL) { ok = 0; break; }
    }
    *flag = ok;
}

__global__ void zero_kernel(float4* __restrict__ p, long long n4) {
    long long i = (long long)blockIdx.x * blockDim.x + threadIdx.x;
    if (i < n4) p[i] = make_float4(0.f, 0.f, 0.f, 0.f);
}

// ---- prepack weights into per-lane MFMA fragment order (bf16), once ----
// frag element i of lane l(=g*16+m? l: g=l>>4,m=l&15), tile ct: B[k=kh*32+g*8+i][n=ct*16+m]
__global__ __launch_bounds__(256) void prepack_kernel(
    const float* __restrict__ w1, const float* __restrict__ w2,
    const float* __restrict__ wo2,
    unsigned short* __restrict__ w1p, unsigned short* __restrict__ w2p,
    unsigned short* __restrict__ wo2p)
{
    int t = blockIdx.x * 256 + threadIdx.x;
    if (t < 256) {                       // w1: [32][64] -> 4 ct tiles
        int ct = t >> 6, l = t & 63, g = l >> 4, m = l & 15;
        #pragma unroll
        for (int i = 0; i < 8; ++i)
            w1p[t * 8 + i] = (unsigned short)f2bf(w1[(g * 8 + i) * F_ + ct * 16 + m]);
    } else if (t < 256 + 512) {          // w2: [64][64] -> kh(2) x ct(4)
        int q = t - 256;
        int kh = q >> 8, ct = (q >> 6) & 3, l = q & 63, g = l >> 4, m = l & 15;
        #pragma unroll
        for (int i = 0; i < 8; ++i)
            w2p[q * 8 + i] = (unsigned short)f2bf(w2[(kh * 32 + g * 8 + i) * F_ + ct * 16 + m]);
    } else if (t < 256 + 512 + 2048) {   // w_o2: [128][128] -> ch(2) x kh(4) x ct(4)
        int q = t - 768;
        int l = q & 63, ct = (q >> 6) & 3, kh = (q >> 8) & 3, ch = q >> 10;
        int g = l >> 4, m = l & 15;
        #pragma unroll
        for (int i = 0; i < 8; ++i)
            wo2p[q * 8 + i] = (unsigned short)f2bf(wo2[(kh * 32 + g * 8 + i) * B_ + ch * 64 + ct * 16 + m]);
    }
}

// ---- h = x @ w_in + b_in, stored bf16 ----
__global__ __launch_bounds__(256) void h_kernel(
    const float* __restrict__ x, const float* __restrict__ w_in,
    const float* __restrict__ b_in, unsigned short* __restrict__ h, int NA)
{
    int n = blockIdx.x * 256 + threadIdx.x;
    if (n >= NA) return;
    float acc[F_];
    #pragma unroll
    for (int f = 0; f < F_; ++f) acc[f] = b_in[f];
    const float4* xrow = (const float4*)(x + (size_t)n * B_);
    #pragma unroll 2
    for (int rb = 0; rb < B_ / 4; ++rb) {
        float4 xv = xrow[rb];
        const float* w0 = w_in + (size_t)(4 * rb) * F_;
        #pragma unroll
        for (int f = 0; f < F_; ++f) acc[f] = fmaf(xv.x, w0[f], acc[f]);
        #pragma unroll
        for (int f = 0; f < F_; ++f) acc[f] = fmaf(xv.y, w0[F_ + f], acc[f]);
        #pragma unroll
        for (int f = 0; f < F_; ++f) acc[f] = fmaf(xv.z, w0[2 * F_ + f], acc[f]);
        #pragma unroll
        for (int f = 0; f < F_; ++f) acc[f] = fmaf(xv.w, w0[3 * F_ + f], acc[f]);
    }
    uint4* hrow = (uint4*)(h + (size_t)n * F_);
    #pragma unroll
    for (int q = 0; q < F_ / 8; ++q) {
        uint4 ob;
        ob.x = f2bf(acc[8 * q + 0]) | (f2bf(acc[8 * q + 1]) << 16);
        ob.y = f2bf(acc[8 * q + 2]) | (f2bf(acc[8 * q + 3]) << 16);
        ob.z = f2bf(acc[8 * q + 4]) | (f2bf(acc[8 * q + 5]) << 16);
        ob.w = f2bf(acc[8 * q + 6]) | (f2bf(acc[8 * q + 7]) << 16);
        hrow[q] = ob;
    }
}

// ---- MFMA fused pair pipeline (v2) ----
// Stage1 SWAPPED: C1[feat][pair] = mfma(w1frag, fijfrag) so each lane holds 4
// consecutive feats of one pair -> packed ds_write_b64 into T[pair][feat] with
// 16B-block XOR swizzle (b ^= wp&7). Stage2 + register scatter = round-2 shape.
__global__ __launch_bounds__(256, 3) void pair_kernel(
    const float* __restrict__ f_ij, const float* __restrict__ rcut,
    const void* __restrict__ pl, const int* __restrict__ flag,
    const unsigned short* __restrict__ w1p, const float* __restrict__ b1,
    const unsigned short* __restrict__ w2p, const float* __restrict__ b2,
    const unsigned short* __restrict__ h, float* __restrict__ agg,
    int P)
{
    __shared__ __align__(16) unsigned short T[256 * 64];  // [pair][feat] bf16, swizzled
    __shared__ __align__(16) int   ii[256];
    __shared__ __align__(16) int   jj[256];
    __shared__ __align__(16) float rr[256];

    const int tid   = threadIdx.x;
    const int lane  = tid & 63;
    const int wv    = tid >> 6;
    const int g     = lane >> 4;
    const int m     = lane & 15;
    const int pbase = blockIdx.x * 256;
    const int wbase = wv * 64;

    // ---- phase 0: pair metadata -> LDS (own wave's slots only) ----
    {
        int p = pbase + tid;
        bool valid = (p < P);
        int pc = valid ? p : (P > 0 ? P - 1 : 0);
        long long i_, j_;
        if (*flag) {
            const long long* p64 = (const long long*)pl;
            i_ = p64[pc]; j_ = p64[(size_t)P + pc];
        } else {
            const int* p32 = (const int*)pl;
            i_ = p32[pc]; j_ = p32[(size_t)P + pc];
        }
        ii[tid] = valid ? (int)i_ : 0;
        jj[tid] = valid ? (int)j_ : 0;
        rr[tid] = valid ? rcut[pc] : 0.0f;
    }

    // ---- prepacked weight fragments: coalesced 16B vector loads ----
    bf16x8 w1f[4], w2f[2][4];
    #pragma unroll
    for (int ct = 0; ct < 4; ++ct)
        w1f[ct] = *(const bf16x8*)&w1p[(ct * 64 + lane) * 8];
    #pragma unroll
    for (int kh = 0; kh < 2; ++kh)
        #pragma unroll
        for (int ct = 0; ct < 4; ++ct)
            w2f[kh][ct] = *(const bf16x8*)&w2p[((kh * 4 + ct) * 64 + lane) * 8];

    float4 b1v[4];
    #pragma unroll
    for (int ft = 0; ft < 4; ++ft) b1v[ft] = *(const float4*)&b1[ft * 16 + g * 4];
    float bias2[4];
    #pragma unroll
    for (int ct = 0; ct < 4; ++ct) bias2[ct] = b2[ct * 16 + m];

    // ---- stage 1 (swapped): C1[ft][pt] = W1^T x f_ij^T ----
    bf16x8 fijf[4];
    #pragma unroll
    for (int pt = 0; pt < 4; ++pt) {
        int row = pbase + wbase + pt * 16 + m;
        if (row >= P) row = (P > 0 ? P - 1 : 0);
        const float* src = f_ij + (size_t)row * R_ + g * 8;
        float4 f0 = *(const float4*)src;
        float4 f1 = *(const float4*)(src + 4);
        short8 a;
        a[0] = (short)f2bf(f0.x); a[1] = (short)f2bf(f0.y);
        a[2] = (short)f2bf(f0.z); a[3] = (short)f2bf(f0.w);
        a[4] = (short)f2bf(f1.x); a[5] = (short)f2bf(f1.y);
        a[6] = (short)f2bf(f1.z); a[7] = (short)f2bf(f1.w);
        fijf[pt] = __builtin_bit_cast(bf16x8, a);
    }
    f32x4 C1[4][4];
    #pragma unroll
    for (int ft = 0; ft < 4; ++ft)
        #pragma unroll
        for (int pt = 0; pt < 4; ++pt) {
            f32x4 z = {0.f, 0.f, 0.f, 0.f};
            C1[ft][pt] = __builtin_amdgcn_mfma_f32_16x16x32_bf16(w1f[ft], fijf[pt], z, 0, 0, 0);
        }

    // ---- ssp + pack 4 feats -> one 8B swizzled T write per tile ----
    // lane: pair wp=pt*16+m, feats ft*16+g*4+r. chunk8 c=ft*4+g, c^=(wp&7)<<1.
    #pragma unroll
    for (int ft = 0; ft < 4; ++ft)
        #pragma unroll
        for (int pt = 0; pt < 4; ++pt) {
            int wp = pt * 16 + m;
            float v0 = sspf(C1[ft][pt][0] + b1v[ft].x);
            float v1 = sspf(C1[ft][pt][1] + b1v[ft].y);
            float v2 = sspf(C1[ft][pt][2] + b1v[ft].z);
            float v3 = sspf(C1[ft][pt][3] + b1v[ft].w);
            uint2 tw;
            tw.x = f2bf(v0) | (f2bf(v1) << 16);
            tw.y = f2bf(v2) | (f2bf(v3) << 16);
            int c = (ft * 4 + g) ^ ((wp & 7) << 1);
            *(uint2*)&T[(wbase + wp) * 64 + c * 4] = tw;
        }

    // ---- stage 2 (round-2 orientation): C2[pair][feat] = T @ W2 ----
    f32x4 C2[4][4];
    #pragma unroll
    for (int rt = 0; rt < 4; ++rt) {
        int wpr = rt * 16 + m;
        int s = wpr & 7;
        const unsigned short* Trow = &T[(wbase + wpr) * 64];
        bf16x8 a0 = *(const bf16x8*)&Trow[((0 + g) ^ s) * 8];
        bf16x8 a1 = *(const bf16x8*)&Trow[((4 + g) ^ s) * 8];
        #pragma unroll
        for (int ct = 0; ct < 4; ++ct) {
            f32x4 c = {0.f, 0.f, 0.f, 0.f};
            c = __builtin_amdgcn_mfma_f32_16x16x32_bf16(a0, w2f[0][ct], c, 0, 0, 0);
            c = __builtin_amdgcn_mfma_f32_16x16x32_bf16(a1, w2f[1][ct], c, 0, 0, 0);
            C2[rt][ct] = c;
        }
    }

    // ---- epilogue: wij*rc*h[j] -> atomic scatter straight from C2 regs ----
    #pragma unroll
    for (int rt = 0; rt < 4; ++rt) {
        int base = wbase + rt * 16 + g * 4;
        int4   iv = *(const int4*)&ii[base];
        int4   jv = *(const int4*)&jj[base];
        float4 rv = *(const float4*)&rr[base];
        int   ia[4] = {iv.x * F_, iv.y * F_, iv.z * F_, iv.w * F_};
        int   ja[4] = {jv.x * F_, jv.y * F_, jv.z * F_, jv.w * F_};
        float ra[4] = {rv.x, rv.y, rv.z, rv.w};
        #pragma unroll
        for (int ct = 0; ct < 4; ++ct) {
            int fcol = ct * 16 + m;
            #pragma unroll
            for (int r = 0; r < 4; ++r) {
                float wij = C2[rt][ct][r] + bias2[ct];
                float hv = bfbits2f(h[ja[r] + fcol]);
                atomicAdd(agg + (ia[r] + fcol), wij * ra[r] * hv);
            }
        }
    }
}

// ---- u = ssp(agg @ w_o1 + b_o1), stored bf16; grid.y = col half ----
__global__ __launch_bounds__(256) void out1_kernel(
    const float* __restrict__ agg, const float* __restrict__ w_o1,
    const float* __restrict__ b_o1, unsigned short* __restrict__ u, int NA)
{
    int n = blockIdx.x * 256 + threadIdx.x;
    if (n >= NA) return;
    int c0 = blockIdx.y * 64;
    float acc[64];
    #pragma unroll
    for (int c = 0; c < 64; ++c) acc[c] = b_o1[c0 + c];
    const float4* arow = (const float4*)(agg + (size_t)n * F_);
    #pragma unroll 2
    for (int rb = 0; rb < F_ / 4; ++rb) {
        float4 av = arow[rb];
        const float* w0 = w_o1 + (size_t)(4 * rb) * B_ + c0;
        #pragma unroll
        for (int c = 0; c < 64; ++c) acc[c] = fmaf(av.x, w0[c], acc[c]);
        #pragma unroll
        for (int c = 0; c < 64; ++c) acc[c] = fmaf(av.y, w0[B_ + c], acc[c]);
        #pragma unroll
        for (int c = 0; c < 64; ++c) acc[c] = fmaf(av.z, w0[2 * B_ + c], acc[c]);
        #pragma unroll
        for (int c = 0; c < 64; ++c) acc[c] = fmaf(av.w, w0[3 * B_ + c], acc[c]);
    }
    uint4* urow = (uint4*)(u + (size_t)n * B_ + c0);
    #pragma unroll
    for (int q = 0; q < 8; ++q) {
        uint4 ob;
        ob.x = f2bf(sspf(acc[8 * q + 0])) | (f2bf(sspf(acc[8 * q + 1])) << 16);
        ob.y = f2bf(sspf(acc[8 * q + 2])) | (f2bf(sspf(acc[8 * q + 3])) << 16);
        ob.z = f2bf(sspf(acc[8 * q + 4])) | (f2bf(sspf(acc[8 * q + 5])) << 16);
        ob.w = f2bf(sspf(acc[8 * q + 6])) | (f2bf(sspf(acc[8 * q + 7])) << 16);
        urow[q] = ob;
    }
}

// ---- out = u @ w_o2 + b_o2 via MFMA; grid.y = col half ----
__global__ __launch_bounds__(256) void out2_kernel(
    const unsigned short* __restrict__ u, const unsigned short* __restrict__ wo2p,
    const float* __restrict__ b_o2, float* __restrict__ out, int NA)
{
    const int tid  = threadIdx.x;
    const int lane = tid & 63;
    const int wv   = tid >> 6;
    const int g    = lane >> 4;
    const int m    = lane & 15;
    const int ch   = blockIdx.y;
    const int rbase = blockIdx.x * 256 + wv * 64;

    bf16x8 wf[4][4];
    #pragma unroll
    for (int kh = 0; kh < 4; ++kh)
        #pragma unroll
        for (int ct = 0; ct < 4; ++ct)
            wf[kh][ct] = *(const bf16x8*)&wo2p[(((ch * 4 + kh) * 4 + ct) * 64 + lane) * 8];
    float bo[4];
    #pragma unroll
    for (int ct = 0; ct < 4; ++ct) bo[ct] = b_o2[ch * 64 + ct * 16 + m];

    f32x4 C[4][4];
    #pragma unroll
    for (int rt = 0; rt < 4; ++rt) {
        int row = rbase + rt * 16 + m;
        if (row >= NA) row = NA - 1;
        const unsigned short* ur = &u[(size_t)row * B_];
        bf16x8 af[4];
        #pragma unroll
        for (int kh = 0; kh < 4; ++kh) af[kh] = *(const bf16x8*)&ur[kh * 32 + g * 8];
        #pragma unroll
        for (int ct = 0; ct < 4; ++ct) {
            f32x4 c = {0.f, 0.f, 0.f, 0.f};
            #pragma unroll
            for (int kh = 0; kh < 4; ++kh)
                c = __builtin_amdgcn_mfma_f32_16x16x32_bf16(af[kh], wf[kh][ct], c, 0, 0, 0);
            C[rt][ct] = c;
        }
    }
    #pragma unroll
    for (int rt = 0; rt < 4; ++rt)
        #pragma unroll
        for (int ct = 0; ct < 4; ++ct)
            #pragma unroll
            for (int r = 0; r < 4; ++r) {
                int ro = rbase + rt * 16 + g * 4 + r;
                if (ro < NA)
                    out[(size_t)ro * B_ + ch * 64 + ct * 16 + m] = C[rt][ct][r] + bo[ct];
            }
}

extern "C" void kernel_launch(void* const* d_in, const int* in_sizes, int n_in,
                              void* d_out, int out_size, void* d_ws, size_t ws_size,
                              hipStream_t stream) {
    const float* x    = (const float*)d_in[0];
    const float* f_ij = (const float*)d_in[1];
    const float* rcut = (const float*)d_in[2];
    const void*  pl   = d_in[3];
    const float* w_in = (const float*)d_in[4];
    const float* b_in = (const float*)d_in[5];
    const float* w_f1 = (const float*)d_in[6];
    const float* b_f1 = (const float*)d_in[7];
    const float* w_f2 = (const float*)d_in[8];
    const float* b_f2 = (const float*)d_in[9];
    const float* w_o1 = (const float*)d_in[10];
    const float* b_o1 = (const float*)d_in[11];
    const float* w_o2 = (const float*)d_in[12];
    const float* b_o2 = (const float*)d_in[13];
    float* out = (float*)d_out;

    int NA = in_sizes[0] / B_;
    int P  = in_sizes[2];

    char* ws = (char*)d_ws;
    size_t off = 0;
    auto alloc = [&](size_t bytes) { size_t o = off; off = (off + bytes + 255) & ~(size_t)255; return o; };
    unsigned short* h_buf = (unsigned short*)(ws + alloc((size_t)NA * F_ * 2));
    float* agg            = (float*)(ws + alloc((size_t)NA * F_ * 4));
    unsigned short* u_buf = (unsigned short*)(ws + alloc((size_t)NA * B_ * 2));
    int* flag             = (int*)(ws + alloc(256));
    unsigned short* w1p   = (unsigned short*)(ws + alloc(2048 * 2));
    unsigned short* w2p   = (unsigned short*)(ws + alloc(4096 * 2));
    unsigned short* wo2p  = (unsigned short*)(ws + alloc(16384 * 2));

    detect_kernel<<<1, 1, 0, stream>>>(pl, flag, P);
    prepack_kernel<<<11, 256, 0, stream>>>(w_f1, w_f2, w_o2, w1p, w2p, wo2p);
    h_kernel<<<(NA + 255) / 256, 256, 0, stream>>>(x, w_in, b_in, h_buf, NA);
    long long n4 = (long long)NA * F_ / 4;
    zero_kernel<<<(int)((n4 + 255) / 256), 256, 0, stream>>>((float4*)agg, n4);
    pair_kernel<<<(P + 255) / 256, 256, 0, stream>>>(f_ij, rcut, pl, flag,
                                                     w1p, b_f1, w2p, b_f2,
                                                     h_buf, agg, P);
    dim3 g3((NA + 255) / 256, 2);
    out1_kernel<<<g3, 256, 0, stream>>>(agg, w_o1, b_o1, u_buf, NA);
    out2_kernel<<<g3, 256, 0, stream>>>(u_buf, wo2p, b_o2, out, NA);
}